// Round 12
// baseline (483.716 us; speedup 1.0000x reference)
//
#include <hip/hip_runtime.h>

#define T_TOK 4096
#define HDIM  1024
#define NEXP  8
#define FFDIM 4096
#define NPAIR 8192   // T_TOK * topk
#define MAXMT 40     // max total 256-row M-tiles across experts: 8192/256 + 8

typedef __attribute__((ext_vector_type(8))) short short8;
typedef __attribute__((ext_vector_type(8))) unsigned short ushort8;
typedef __attribute__((ext_vector_type(4))) float f32x4;

__device__ __forceinline__ unsigned short f2bf(float f) {
  unsigned int u = __float_as_uint(f);
  u += 0x7fffu + ((u >> 16) & 1u);   // RNE
  return (unsigned short)(u >> 16);
}

// global -> LDS direct copy, 16B per lane. LDS dest is wave-uniform base;
// HW writes lane l at base + l*16. Global source address is per-lane.
__device__ __forceinline__ void gload16(const void* g, const void* l) {
  __builtin_amdgcn_global_load_lds(
      (const __attribute__((address_space(1))) unsigned int*)(unsigned long long)g,
      (__attribute__((address_space(3))) unsigned int*)(unsigned int)(unsigned long long)l,
      16, 0, 0);
}

// [M][N] fp32 -> [N][M] bf16, per-expert (blockIdx.z), 64x64 tiles
__global__ __launch_bounds__(256) void transpose_bf16_kernel(
    const float* __restrict__ in, unsigned short* __restrict__ out, int M, int N) {
  in  += (size_t)blockIdx.z * M * N;
  out += (size_t)blockIdx.z * M * N;
  __shared__ unsigned short t[64][72];
  int tid = threadIdx.x;
  int r0 = blockIdx.y * 64, c0 = blockIdx.x * 64;
#pragma unroll
  for (int rr = 0; rr < 4; rr++) {
    int row = rr * 16 + (tid >> 4);
    int col = (tid & 15) * 4;
    float4 v = *(const float4*)(in + (size_t)(r0 + row) * N + c0 + col);
    t[col + 0][row] = f2bf(v.x);
    t[col + 1][row] = f2bf(v.y);
    t[col + 2][row] = f2bf(v.z);
    t[col + 3][row] = f2bf(v.w);
  }
  __syncthreads();
#pragma unroll
  for (int rr = 0; rr < 2; rr++) {
    int c = rr * 32 + (tid >> 3);
    int m0 = (tid & 7) * 8;
    ushort8 v = *(const ushort8*)&t[c][m0];
    *(ushort8*)(out + (size_t)(c0 + c) * M + r0 + m0) = v;
  }
}

// ---------------- router (fused: also emits bf16 x) ----------------

__global__ __launch_bounds__(256) void router_kernel(
    const float* __restrict__ x, const float* __restrict__ wg,
    unsigned short* __restrict__ xb,
    int* __restrict__ sel_e, float* __restrict__ sel_w, int* __restrict__ counts) {
  int lane = threadIdx.x & 63;
  int t = blockIdx.x * 4 + (threadIdx.x >> 6);
  const float* xr = x + (size_t)t * HDIM;
  unsigned short* xo = xb + (size_t)t * HDIM;
  float acc[8] = {0, 0, 0, 0, 0, 0, 0, 0};
  for (int i = 0; i < HDIM / 64; i++) {
    int h = i * 64 + lane;
    float xv = xr[h];
    xo[h] = f2bf(xv);                        // fused convert_x
    float4 w0 = *(const float4*)(wg + h * 8);
    float4 w1 = *(const float4*)(wg + h * 8 + 4);
    acc[0] += xv * w0.x; acc[1] += xv * w0.y; acc[2] += xv * w0.z; acc[3] += xv * w0.w;
    acc[4] += xv * w1.x; acc[5] += xv * w1.y; acc[6] += xv * w1.z; acc[7] += xv * w1.w;
  }
#pragma unroll
  for (int off = 32; off > 0; off >>= 1) {
#pragma unroll
    for (int e = 0; e < 8; e++) acc[e] += __shfl_xor(acc[e], off, 64);
  }
  if (lane == 0) {
    int e0 = 0; float b0 = acc[0];
#pragma unroll
    for (int e = 1; e < 8; e++) if (acc[e] > b0) { b0 = acc[e]; e0 = e; }
    int e1 = -1; float b1 = -3.4e38f;
#pragma unroll
    for (int e = 0; e < 8; e++) if (e != e0 && acc[e] > b1) { b1 = acc[e]; e1 = e; }
    float q = expf(b1 - b0);                 // softmax denominator cancels in renorm
    float w0 = 1.0f / (1.0f + q);
    float w1 = q / (1.0f + q);
    sel_e[t * 2] = e0; sel_e[t * 2 + 1] = e1;
    sel_w[t * 2] = w0; sel_w[t * 2 + 1] = w1;
    atomicAdd(&counts[e0], 1);
    atomicAdd(&counts[e1], 1);
  }
}

__global__ void offsets_kernel(const int* __restrict__ counts,
                               int* __restrict__ offsets, int* __restrict__ cursor) {
  if (threadIdx.x == 0 && blockIdx.x == 0) {
    int s = 0;
    for (int e = 0; e < NEXP; e++) { offsets[e] = s; cursor[e] = s; s += counts[e]; }
  }
}

__global__ __launch_bounds__(256) void scatter_kernel(
    const int* __restrict__ sel_e, const float* __restrict__ sel_w,
    int* __restrict__ cursor, int* __restrict__ pair_token, float* __restrict__ pair_w) {
  int t = blockIdx.x * 256 + threadIdx.x;
#pragma unroll
  for (int j = 0; j < 2; j++) {
    int e = sel_e[t * 2 + j];
    int pos = atomicAdd(&cursor[e], 1);
    pair_token[pos] = t;
    pair_w[pos] = sel_w[t * 2 + j];
  }
}

// --- expert GEMMs: m201 8-phase port. 256x256, BK=64, 8 waves, 128KB LDS ---
// LDS = 2 bufs x 4 half-slots {A-kk0@0, A-kk1@16K, B-kk0@32K, B-kk1@48K},
// half = 256 rows x 32K bf16 = 16KB = 2 gload16. Wave tile 128x64, acc[8][4].
// 4 phases per K-tile t (buf bb=t&1), quadrant = (kk, n-half). Per phase:
// {ds_read frags ; stage 1 half-tile ; BAR ; setprio 16 MFMA ; BAR}.
//  p1: read af[8](kk0)+bf01(kk0,nh0); stage (t+1).B1 -> buf t+1
//  p2: read bf23(kk0,nh1) [af reg-cached]; stage (t+2).A0 -> buf t (A0 dead: its
//      last ds_read was p1, separated by p1's closing barrier -> WAR-safe)
//  p3: read af[8](kk1)+bf01(kk1,nh0); stage (t+2).B0 -> buf t (B0 dead after p2)
//  p4: read bf23(kk1,nh1); stage (t+2).A1; vmcnt -> BAR -> MFMA -> BAR
// Stage order = consumption order [A0,B0,A1,B1], h(4t..4t+3) per tile; staging
// runs 7 half-tiles ahead. vmcnt(6) at p4: outstanding = h(4t+4..4t+10) = 14
// loads; proves tile t+1 fully landed, 3 half-tiles (6 loads) stay in flight —
// never drains mid-loop (m97-ceiling mechanism). Tail: at t=NT-2 p4 -> vmcnt(0)
// (nothing newer in flight: r3/r4 lesson). vmcnt BEFORE its barrier (r7).
// Swizzle (r9 pair, measured 0 conflicts): 64B rows = 4 slots; slot s of row r
// holds chunk s^((r>>1)&3); read chunk g at slot g^((lr>>1)&3).
template <int KD, int KSPL, bool GATHER, bool SQRELU>
__global__ __launch_bounds__(512, 1) void moe_gemm_kernel(
    const unsigned short* __restrict__ A0g, const unsigned short* __restrict__ B0g,
    const int* __restrict__ counts,
    const int* __restrict__ pair_token, const float* __restrict__ pair_w,
    unsigned short* __restrict__ h1out, float* __restrict__ out) {
  constexpr int ND = SQRELU ? FFDIM : HDIM;
  constexpr int KLEN = KD / KSPL;
  constexpr int NTILES = KLEN / 64;

  // XCD-chunked bijective swizzle (gridDim.x % 8 == 0); mt fastest
  int d = blockIdx.x;
  int nb = gridDim.x;
  int w = (d & 7) * (nb >> 3) + (d >> 3);
  int mt = w % MAXMT;
  int rest = w / MAXMT;
  int ks = rest % KSPL;
  int nt = rest / KSPL;

  // ---- expert-tile search (wave-uniform) ----
  int eSel = -1, tloc = 0, segstart = 0, segcnt = 0;
  {
    int cumt = 0, acc = 0;
#pragma unroll
    for (int ee = 0; ee < NEXP; ee++) {
      int c = counts[ee];
      int ntl = (c + 255) >> 8;
      if (eSel < 0 && mt < cumt + ntl) { eSel = ee; tloc = mt - cumt; segstart = acc; segcnt = c; }
      cumt += ntl; acc += c;
    }
  }
  if (eSel < 0) return;

  const unsigned short* B = B0g + (size_t)eSel * ND * KD + (size_t)ks * KLEN;
  const unsigned short* Abase = A0g + (size_t)ks * KLEN;

  int tid = threadIdx.x;
  int lane = tid & 63;
  int wv = tid >> 6;       // 0..7
  int wr = wv >> 2;        // 0..1  (M: rows wr*128..+127)
  int wc = wv & 3;         // 0..3  (N: cols wc*64..+63)
  int g  = lane >> 4;      // 0..3
  int lr = lane & 15;

  // staging: gload r covers rows r*128 + (tid>>2); 4 threads per 64B half-row
  int srow = tid >> 2;                       // 0..127
  int schunk = (tid & 3) ^ ((tid >> 3) & 3); // pre-swizzled source chunk (16B)
  const unsigned short* aP[2];
  const unsigned short* bP[2];
#pragma unroll
  for (int r = 0; r < 2; r++) {
    int arow = r * 128 + srow;
    int idx = tloc * 256 + arow;
    if (idx >= segcnt) idx = segcnt - 1;     // clamp pad rows
    int p = segstart + idx;
    size_t rowoff;
    if (GATHER) rowoff = (size_t)pair_token[p] * KD;
    else        rowoff = (size_t)p * KD;
    aP[r] = Abase + rowoff + schunk * 8;
    bP[r] = B + (size_t)(nt * 256 + r * 128 + srow) * KD + schunk * 8;
  }

  __shared__ char lds[131072];   // 2 bufs x {A0@0, A1@16K, B0@32K, B1@48K}
  const char* ldsc = lds;
  int ldsW = wv * 1024;          // wave-uniform (lane*16 added by HW)

  // per-thread LDS read bases (within a buf); + kk*16384 + frag*1024
  int swz = (g ^ ((lr >> 1) & 3)) * 16;
  int aBase0 = (wr * 128 + lr) * 64 + swz;           // + mi*1024
  int bBase0 = 32768 + (wc * 64 + lr) * 64 + swz;    // + (nh*2+f)*1024

  f32x4 acc[8][4];
#pragma unroll
  for (int i = 0; i < 8; i++)
#pragma unroll
    for (int j = 0; j < 4; j++) acc[i][j] = (f32x4){0.f, 0.f, 0.f, 0.f};

  // prologue: stage h0..h6 = tile0.{A0,B0,A1,B1} + tile1.{A0,B0,A1}
#pragma unroll
  for (int r = 0; r < 2; r++) gload16(aP[r], ldsc + r * 8192 + ldsW);             // t0.A0
#pragma unroll
  for (int r = 0; r < 2; r++) gload16(bP[r], ldsc + 32768 + r * 8192 + ldsW);     // t0.B0
#pragma unroll
  for (int r = 0; r < 2; r++) gload16(aP[r] + 32, ldsc + 16384 + r * 8192 + ldsW);// t0.A1
#pragma unroll
  for (int r = 0; r < 2; r++) gload16(bP[r] + 32, ldsc + 49152 + r * 8192 + ldsW);// t0.B1
#pragma unroll
  for (int r = 0; r < 2; r++) { aP[r] += 64; bP[r] += 64; }                       // -> tile1
  if (NTILES > 1) {
#pragma unroll
    for (int r = 0; r < 2; r++) gload16(aP[r], ldsc + 65536 + r * 8192 + ldsW);          // t1.A0
#pragma unroll
    for (int r = 0; r < 2; r++) gload16(bP[r], ldsc + 65536 + 32768 + r * 8192 + ldsW);  // t1.B0
#pragma unroll
    for (int r = 0; r < 2; r++) gload16(aP[r] + 32, ldsc + 65536 + 16384 + r * 8192 + ldsW); // t1.A1
  }
  asm volatile("s_waitcnt vmcnt(6)" ::: "memory");   // tile0 proven; 3 halves in flight
  __builtin_amdgcn_s_barrier();
  __builtin_amdgcn_sched_barrier(0);

  for (int t = 0; t < NTILES; ++t) {
    int bb = (t & 1) * 65536;
    int sb = bb ^ 65536;
    bool pf1 = (t + 1 < NTILES);
    bool pf2 = (t + 2 < NTILES);
    short8 af[8], bf[2];

    // ---- phase 1: af(kk0) + bf(kk0,nh0); stage (t+1).B1 ----
#pragma unroll
    for (int mi = 0; mi < 8; mi++)
      af[mi] = *(const short8*)(ldsc + bb + aBase0 + mi * 1024);
#pragma unroll
    for (int f = 0; f < 2; f++)
      bf[f] = *(const short8*)(ldsc + bb + bBase0 + f * 1024);
    if (pf1) {
      gload16(bP[0] + 32, ldsc + sb + 49152 + ldsW);
      gload16(bP[1] + 32, ldsc + sb + 49152 + 8192 + ldsW);
    }
    __builtin_amdgcn_s_barrier();
    __builtin_amdgcn_sched_barrier(0);
    __builtin_amdgcn_s_setprio(1);
#pragma unroll
    for (int mi = 0; mi < 8; mi++)
#pragma unroll
      for (int f = 0; f < 2; f++)
        acc[mi][f] = __builtin_amdgcn_mfma_f32_16x16x32_bf16(af[mi], bf[f], acc[mi][f], 0, 0, 0);
    __builtin_amdgcn_s_setprio(0);
    __builtin_amdgcn_s_barrier();
    __builtin_amdgcn_sched_barrier(0);

    // ---- phase 2: bf(kk0,nh1); stage (t+2).A0 -> bb (A0 dead since p1) ----
#pragma unroll
    for (int f = 0; f < 2; f++)
      bf[f] = *(const short8*)(ldsc + bb + bBase0 + (2 + f) * 1024);
    if (pf2) {
      gload16(aP[0] + 64, ldsc + bb + ldsW);
      gload16(aP[1] + 64, ldsc + bb + 8192 + ldsW);
    }
    __builtin_amdgcn_s_barrier();
    __builtin_amdgcn_sched_barrier(0);
    __builtin_amdgcn_s_setprio(1);
#pragma unroll
    for (int mi = 0; mi < 8; mi++)
#pragma unroll
      for (int f = 0; f < 2; f++)
        acc[mi][2 + f] = __builtin_amdgcn_mfma_f32_16x16x32_bf16(af[mi], bf[f], acc[mi][2 + f], 0, 0, 0);
    __builtin_amdgcn_s_setprio(0);
    __builtin_amdgcn_s_barrier();
    __builtin_amdgcn_sched_barrier(0);

    // ---- phase 3: af(kk1) + bf(kk1,nh0); stage (t+2).B0 -> bb ----
#pragma unroll
    for (int mi = 0; mi < 8; mi++)
      af[mi] = *(const short8*)(ldsc + bb + 16384 + aBase0 + mi * 1024);
#pragma unroll
    for (int f = 0; f < 2; f++)
      bf[f] = *(const short8*)(ldsc + bb + 16384 + bBase0 + f * 1024);
    if (pf2) {
      gload16(bP[0] + 64, ldsc + bb + 32768 + ldsW);
      gload16(bP[1] + 64, ldsc + bb + 32768 + 8192 + ldsW);
    }
    __builtin_amdgcn_s_barrier();
    __builtin_amdgcn_sched_barrier(0);
    __builtin_amdgcn_s_setprio(1);
#pragma unroll
    for (int mi = 0; mi < 8; mi++)
#pragma unroll
      for (int f = 0; f < 2; f++)
        acc[mi][f] = __builtin_amdgcn_mfma_f32_16x16x32_bf16(af[mi], bf[f], acc[mi][f], 0, 0, 0);
    __builtin_amdgcn_s_setprio(0);
    __builtin_amdgcn_s_barrier();
    __builtin_amdgcn_sched_barrier(0);

    // ---- phase 4: bf(kk1,nh1); stage (t+2).A1 -> bb; vmcnt; advance ----
#pragma unroll
    for (int f = 0; f < 2; f++)
      bf[f] = *(const short8*)(ldsc + bb + 16384 + bBase0 + (2 + f) * 1024);
    if (pf2) {
      gload16(aP[0] + 96, ldsc + bb + 16384 + ldsW);
      gload16(aP[1] + 96, ldsc + bb + 16384 + 8192 + ldsW);
#pragma unroll
      for (int r = 0; r < 2; r++) { aP[r] += 64; bP[r] += 64; }
      asm volatile("s_waitcnt vmcnt(6)" ::: "memory");  // tile t+1 proven; 3 halves fly
    } else if (pf1) {
      asm volatile("s_waitcnt vmcnt(0)" ::: "memory");  // tail: prove tile t+1 fully
    }
    __builtin_amdgcn_s_barrier();
    __builtin_amdgcn_sched_barrier(0);
    __builtin_amdgcn_s_setprio(1);
#pragma unroll
    for (int mi = 0; mi < 8; mi++)
#pragma unroll
      for (int f = 0; f < 2; f++)
        acc[mi][2 + f] = __builtin_amdgcn_mfma_f32_16x16x32_bf16(af[mi], bf[f], acc[mi][2 + f], 0, 0, 0);
    __builtin_amdgcn_s_setprio(0);
    __builtin_amdgcn_s_barrier();
    __builtin_amdgcn_sched_barrier(0);
  }

  // ---- epilogue: C/D layout col=lane&15, row=(lane>>4)*4+q ----
  int colb = nt * 256 + wc * 64 + lr;        // + nj*16
  int rowb = tloc * 256 + wr * 128 + g * 4;  // + mi*16 + q
#pragma unroll
  for (int mi = 0; mi < 8; mi++) {
#pragma unroll
    for (int q = 0; q < 4; q++) {
      int idx = rowb + mi * 16 + q;
      if (idx < segcnt) {
        int p = segstart + idx;
        if (SQRELU) {
          size_t ro = (size_t)p * FFDIM + colb;
#pragma unroll
          for (int nj = 0; nj < 4; nj++) {
            float v = acc[mi][nj][q];
            v = v > 0.f ? v * v : 0.f;
            h1out[ro + nj * 16] = f2bf(v);
          }
        } else {
          int tok = pair_token[p];
          float wgt = pair_w[p];
          size_t ro = (size_t)tok * HDIM + colb;
#pragma unroll
          for (int nj = 0; nj < 4; nj++)
            atomicAdd(out + ro + nj * 16, acc[mi][nj][q] * wgt);
        }
      }
    }
  }
}

// ---------------- launch ----------------

extern "C" void kernel_launch(void* const* d_in, const int* in_sizes, int n_in,
                              void* d_out, int out_size, void* d_ws, size_t ws_size,
                              hipStream_t stream) {
  (void)in_sizes; (void)n_in; (void)out_size; (void)ws_size;
  const float* x     = (const float*)d_in[0];
  const float* Wg    = (const float*)d_in[1];
  const float* Wfc   = (const float*)d_in[2];
  const float* Wproj = (const float*)d_in[3];
  float* out = (float*)d_out;

  char* w = (char*)d_ws;
  size_t o = 0;
  auto take = [&](size_t n) { char* p = w + o; o += (n + 255) & ~(size_t)255; return p; };
  unsigned short* xb     = (unsigned short*)take((size_t)T_TOK * HDIM * 2);
  unsigned short* WfcT   = (unsigned short*)take((size_t)NEXP * FFDIM * HDIM * 2);
  unsigned short* WprojT = (unsigned short*)take((size_t)NEXP * HDIM * FFDIM * 2);
  unsigned short* h1     = (unsigned short*)take((size_t)NPAIR * FFDIM * 2);
  int*   sel_e      = (int*)take(T_TOK * 2 * 4);
  float* sel_w      = (float*)take(T_TOK * 2 * 4);
  int*   pair_token = (int*)take(NPAIR * 4);
  float* pair_w     = (float*)take(NPAIR * 4);
  int*   counts     = (int*)take(3 * 8 * 4);
  int*   offsets    = counts + 8;
  int*   cursor     = counts + 16;

  hipMemsetAsync(out, 0, (size_t)T_TOK * HDIM * 4, stream);
  hipMemsetAsync(counts, 0, 96, stream);

  router_kernel<<<T_TOK / 4, 256, 0, stream>>>(x, Wg, xb, sel_e, sel_w, counts);
  transpose_bf16_kernel<<<dim3(FFDIM / 64, HDIM / 64, NEXP), 256, 0, stream>>>(Wfc, WfcT, HDIM, FFDIM);
  transpose_bf16_kernel<<<dim3(HDIM / 64, FFDIM / 64, NEXP), 256, 0, stream>>>(Wproj, WprojT, FFDIM, HDIM);
  offsets_kernel<<<1, 64, 0, stream>>>(counts, offsets, cursor);
  scatter_kernel<<<T_TOK / 256, 256, 0, stream>>>(sel_e, sel_w, cursor, pair_token, pair_w);

  // GEMM1: per expert, [seg x 1024] x [1024 x 4096] -> relu^2 -> h1 (bf16)
  moe_gemm_kernel<HDIM, 1, true, true>
      <<<(FFDIM / 256) * MAXMT, 512, 0, stream>>>(xb, WfcT, counts,
                                                  pair_token, pair_w, h1, nullptr);
  // GEMM2: per expert, [seg x 4096] x [4096 x 1024] -> weighted combine, split-K=4
  moe_gemm_kernel<FFDIM, 4, false, false>
      <<<(HDIM / 256) * 4 * MAXMT, 512, 0, stream>>>(h1, WprojT, counts,
                                                     pair_token, pair_w, nullptr, out);
}

// Round 13
// 430.470 us; speedup vs baseline: 1.1237x; 1.1237x over previous
//
#include <hip/hip_runtime.h>

#define T_TOK 4096
#define HDIM  1024
#define NEXP  8
#define FFDIM 4096
#define NPAIR 8192   // T_TOK * topk
#define MAXMT 72     // max total 128-row M-tiles across experts: 8192/128 + 8

typedef __attribute__((ext_vector_type(8))) short short8;
typedef __attribute__((ext_vector_type(8))) unsigned short ushort8;
typedef __attribute__((ext_vector_type(4))) float f32x4;

__device__ __forceinline__ unsigned short f2bf(float f) {
  unsigned int u = __float_as_uint(f);
  u += 0x7fffu + ((u >> 16) & 1u);   // RNE
  return (unsigned short)(u >> 16);
}

// global -> LDS direct copy, 16B per lane. LDS dest is wave-uniform base;
// HW writes lane l at base + l*16. Global source address is per-lane.
__device__ __forceinline__ void gload16(const void* g, const void* l) {
  __builtin_amdgcn_global_load_lds(
      (const __attribute__((address_space(1))) unsigned int*)(unsigned long long)g,
      (__attribute__((address_space(3))) unsigned int*)(unsigned int)(unsigned long long)l,
      16, 0, 0);
}

// [M][N] fp32 -> [N][M] bf16, per-expert (blockIdx.z), 64x64 tiles
__global__ __launch_bounds__(256) void transpose_bf16_kernel(
    const float* __restrict__ in, unsigned short* __restrict__ out, int M, int N) {
  in  += (size_t)blockIdx.z * M * N;
  out += (size_t)blockIdx.z * M * N;
  __shared__ unsigned short t[64][72];
  int tid = threadIdx.x;
  int r0 = blockIdx.y * 64, c0 = blockIdx.x * 64;
#pragma unroll
  for (int rr = 0; rr < 4; rr++) {
    int row = rr * 16 + (tid >> 4);
    int col = (tid & 15) * 4;
    float4 v = *(const float4*)(in + (size_t)(r0 + row) * N + c0 + col);
    t[col + 0][row] = f2bf(v.x);
    t[col + 1][row] = f2bf(v.y);
    t[col + 2][row] = f2bf(v.z);
    t[col + 3][row] = f2bf(v.w);
  }
  __syncthreads();
#pragma unroll
  for (int rr = 0; rr < 2; rr++) {
    int c = rr * 32 + (tid >> 3);
    int m0 = (tid & 7) * 8;
    ushort8 v = *(const ushort8*)&t[c][m0];
    *(ushort8*)(out + (size_t)(c0 + c) * M + r0 + m0) = v;
  }
}

// ---------------- router (fused: also emits bf16 x) ----------------

__global__ __launch_bounds__(256) void router_kernel(
    const float* __restrict__ x, const float* __restrict__ wg,
    unsigned short* __restrict__ xb,
    int* __restrict__ sel_e, float* __restrict__ sel_w, int* __restrict__ counts) {
  int lane = threadIdx.x & 63;
  int t = blockIdx.x * 4 + (threadIdx.x >> 6);
  const float* xr = x + (size_t)t * HDIM;
  unsigned short* xo = xb + (size_t)t * HDIM;
  float acc[8] = {0, 0, 0, 0, 0, 0, 0, 0};
  for (int i = 0; i < HDIM / 64; i++) {
    int h = i * 64 + lane;
    float xv = xr[h];
    xo[h] = f2bf(xv);                        // fused convert_x
    float4 w0 = *(const float4*)(wg + h * 8);
    float4 w1 = *(const float4*)(wg + h * 8 + 4);
    acc[0] += xv * w0.x; acc[1] += xv * w0.y; acc[2] += xv * w0.z; acc[3] += xv * w0.w;
    acc[4] += xv * w1.x; acc[5] += xv * w1.y; acc[6] += xv * w1.z; acc[7] += xv * w1.w;
  }
#pragma unroll
  for (int off = 32; off > 0; off >>= 1) {
#pragma unroll
    for (int e = 0; e < 8; e++) acc[e] += __shfl_xor(acc[e], off, 64);
  }
  if (lane == 0) {
    int e0 = 0; float b0 = acc[0];
#pragma unroll
    for (int e = 1; e < 8; e++) if (acc[e] > b0) { b0 = acc[e]; e0 = e; }
    int e1 = -1; float b1 = -3.4e38f;
#pragma unroll
    for (int e = 0; e < 8; e++) if (e != e0 && acc[e] > b1) { b1 = acc[e]; e1 = e; }
    float q = expf(b1 - b0);                 // softmax denominator cancels in renorm
    float w0 = 1.0f / (1.0f + q);
    float w1 = q / (1.0f + q);
    sel_e[t * 2] = e0; sel_e[t * 2 + 1] = e1;
    sel_w[t * 2] = w0; sel_w[t * 2 + 1] = w1;
    atomicAdd(&counts[e0], 1);
    atomicAdd(&counts[e1], 1);
  }
}

__global__ void offsets_kernel(const int* __restrict__ counts,
                               int* __restrict__ offsets, int* __restrict__ cursor) {
  if (threadIdx.x == 0 && blockIdx.x == 0) {
    int s = 0;
    for (int e = 0; e < NEXP; e++) { offsets[e] = s; cursor[e] = s; s += counts[e]; }
  }
}

__global__ __launch_bounds__(256) void scatter_kernel(
    const int* __restrict__ sel_e, const float* __restrict__ sel_w,
    int* __restrict__ cursor, int* __restrict__ pair_token, float* __restrict__ pair_w) {
  int t = blockIdx.x * 256 + threadIdx.x;
#pragma unroll
  for (int j = 0; j < 2; j++) {
    int e = sel_e[t * 2 + j];
    int pos = atomicAdd(&cursor[e], 1);
    pair_token[pos] = t;
    pair_w[pos] = sel_w[t * 2 + j];
  }
}

// --- expert GEMMs: r9 structure (best measured: 127us/dispatch, 431 total) ---
// 128x256 tile, BK=32, 3-slot ring (72KB), 8 waves (2M x 4N), wave tile 64x64,
// acc[4][4] (~60 VGPR + 64 AGPR -> 4 waves/SIMD, 2 blocks/CU). Per K-tile:
//   vmcnt(3) [own newest 3 = t+1's, so tile t fully landed] -> s_barrier
//   [global RAW] -> 8 ds_read(slot t) -> stage t+2 (3 gload16 -> slot t-1)
//   -> setprio(1) 16 MFMA. Last tile: vmcnt(0) (r3/r4 lesson).
// vmcnt BEFORE barrier (r7 lesson). WAR: stage into slot t-1 after bar(t);
// all reads of slot t-1 happened before bar(t).
// Swizzle (r2/r9 pair, measured 0 conflicts): 64B rows = 4 chunks of 16B;
// store chunk (tid&3)^((tid>>3)&3), read chunk g at slot g^((lr>>1)&3).
// Work order (CHANGED vs r9): nt fastest within XCD chunk. Chunk of 144 blocks
// = ~9 M-tiles x 16 nt: the ~2.3MB of (gathered, 128B-granular) A rows stays
// L2-resident while dense B panels restream from L3. r9's mt-fastest re-read
// the full 16.8MB A set per nt (L2 4MB thrash -> FETCH 173MB >> 84MB unique).
template <int KD, int KSPL, int NTP, bool GATHER, bool SQRELU>
__global__ __launch_bounds__(512, 4) void moe_gemm_kernel(
    const unsigned short* __restrict__ A0, const unsigned short* __restrict__ B0,
    const int* __restrict__ counts,
    const int* __restrict__ pair_token, const float* __restrict__ pair_w,
    unsigned short* __restrict__ h1out, float* __restrict__ out) {
  constexpr int ND = SQRELU ? FFDIM : HDIM;
  constexpr int KLEN = KD / KSPL;
  constexpr int NTILES = KLEN / 32;

  // XCD-chunked bijective swizzle (gridDim.x % 8 == 0); nt fastest
  int d = blockIdx.x;
  int nb = gridDim.x;
  int w = (d & 7) * (nb >> 3) + (d >> 3);
  int nt = w % NTP;
  int rest = w / NTP;
  int ks = rest % KSPL;
  int mt = rest / KSPL;

  // ---- expert-tile search (wave-uniform) ----
  int eSel = -1, tloc = 0, segstart = 0, segcnt = 0;
  {
    int cumt = 0, acc = 0;
#pragma unroll
    for (int ee = 0; ee < NEXP; ee++) {
      int c = counts[ee];
      int ntl = (c + 127) >> 7;
      if (eSel < 0 && mt < cumt + ntl) { eSel = ee; tloc = mt - cumt; segstart = acc; segcnt = c; }
      cumt += ntl; acc += c;
    }
  }
  if (eSel < 0) return;

  const unsigned short* B = B0 + (size_t)eSel * ND * KD + (size_t)ks * KLEN;
  const unsigned short* Abase = A0 + (size_t)ks * KLEN;

  int tid = threadIdx.x;
  int lane = tid & 63;
  int wv = tid >> 6;       // 0..7
  int wr = wv >> 2;        // 0..1  (M: rows wr*64..+63)
  int wc = wv & 3;         // 0..3  (N: cols wc*64..+63)
  int g  = lane >> 4;      // 0..3
  int lr = lane & 15;

  // staging: A rows tid>>2 (0..127, 1 gload); B rows r*128 + tid>>2 (2 gloads)
  int srow = tid >> 2;                       // 0..127
  int schunk = (tid & 3) ^ ((tid >> 3) & 3); // pre-swizzled source chunk
  const unsigned short* aP;
  const unsigned short* bP[2];
  {
    int idx = tloc * 128 + srow;
    if (idx >= segcnt) idx = segcnt - 1;     // clamp pad rows
    int p = segstart + idx;
    size_t rowoff;
    if (GATHER) rowoff = (size_t)pair_token[p] * KD;
    else        rowoff = (size_t)p * KD;
    aP = Abase + rowoff + schunk * 8;
#pragma unroll
    for (int r = 0; r < 2; r++)
      bP[r] = B + (size_t)(nt * 256 + r * 128 + srow) * KD + schunk * 8;
  }

  __shared__ char lds[73728];          // 3 slots x (A 8KB + B 16KB)
  const char* ldsc = lds;
  int ldsW = wv * 1024;                // wave-uniform (lane*16 added by HW)

  f32x4 acc[4][4];
#pragma unroll
  for (int i = 0; i < 4; i++)
#pragma unroll
    for (int j = 0; j < 4; j++) acc[i][j] = (f32x4){0.f, 0.f, 0.f, 0.f};

  // per-thread LDS read bases (within a slot)
  int swz = (g ^ ((lr >> 1) & 3)) * 16;
  int abase0 = (wr * 64 + lr) * 64 + swz;            // + mi*1024
  int bbase0 = 8192 + (wc * 64 + lr) * 64 + swz;     // + nj*1024

  // prologue: stage tiles 0 and 1 into slots 0,1
#pragma unroll
  for (int t = 0; t < 2; t++) {
    int so = t * 24576;
    gload16(aP, ldsc + so + ldsW);
    gload16(bP[0], ldsc + so + 8192 + ldsW);
    gload16(bP[1], ldsc + so + 16384 + ldsW);
    aP += 32; bP[0] += 32; bP[1] += 32;
  }

  int rsOff = 0, rs2Off = 49152;
  for (int t = 0; t < NTILES; ++t) {
    // own newest 3 = t+1's loads; everything older (tile t) forced complete.
    if (t < NTILES - 1) {
      asm volatile("s_waitcnt vmcnt(3)" ::: "memory");
    } else {
      asm volatile("s_waitcnt vmcnt(0)" ::: "memory");
    }
    __builtin_amdgcn_s_barrier();
    __builtin_amdgcn_sched_barrier(0);

    short8 af[4], bf[4];
#pragma unroll
    for (int mi = 0; mi < 4; mi++)
      af[mi] = *(const short8*)(ldsc + rsOff + abase0 + mi * 1024);
#pragma unroll
    for (int nj = 0; nj < 4; nj++)
      bf[nj] = *(const short8*)(ldsc + rsOff + bbase0 + nj * 1024);

    if (t + 2 < NTILES) {              // stage tile t+2 into slot of tile t-1
      gload16(aP, ldsc + rs2Off + ldsW);
      gload16(bP[0], ldsc + rs2Off + 8192 + ldsW);
      gload16(bP[1], ldsc + rs2Off + 16384 + ldsW);
      aP += 32; bP[0] += 32; bP[1] += 32;
    }

    __builtin_amdgcn_s_setprio(1);
#pragma unroll
    for (int mi = 0; mi < 4; mi++)
#pragma unroll
      for (int nj = 0; nj < 4; nj++)
        acc[mi][nj] = __builtin_amdgcn_mfma_f32_16x16x32_bf16(af[mi], bf[nj], acc[mi][nj], 0, 0, 0);
    __builtin_amdgcn_s_setprio(0);

    rsOff  = (rsOff  == 49152) ? 0 : rsOff  + 24576;
    rs2Off = (rs2Off == 49152) ? 0 : rs2Off + 24576;
  }

  // ---- epilogue: C/D layout col=lane&15, row=(lane>>4)*4+q ----
  int colb = nt * 256 + wc * 64 + lr;        // + nj*16
  int rowb = tloc * 128 + wr * 64 + g * 4;   // + mi*16 + q
#pragma unroll
  for (int mi = 0; mi < 4; mi++) {
#pragma unroll
    for (int q = 0; q < 4; q++) {
      int idx = rowb + mi * 16 + q;
      if (idx < segcnt) {
        int p = segstart + idx;
        if (SQRELU) {
          size_t ro = (size_t)p * FFDIM + colb;
#pragma unroll
          for (int nj = 0; nj < 4; nj++) {
            float v = acc[mi][nj][q];
            v = v > 0.f ? v * v : 0.f;
            h1out[ro + nj * 16] = f2bf(v);
          }
        } else {
          int tok = pair_token[p];
          float wgt = pair_w[p];
          size_t ro = (size_t)tok * HDIM + colb;
#pragma unroll
          for (int nj = 0; nj < 4; nj++)
            atomicAdd(out + ro + nj * 16, acc[mi][nj][q] * wgt);
        }
      }
    }
  }
}

// ---------------- launch ----------------

extern "C" void kernel_launch(void* const* d_in, const int* in_sizes, int n_in,
                              void* d_out, int out_size, void* d_ws, size_t ws_size,
                              hipStream_t stream) {
  (void)in_sizes; (void)n_in; (void)out_size; (void)ws_size;
  const float* x     = (const float*)d_in[0];
  const float* Wg    = (const float*)d_in[1];
  const float* Wfc   = (const float*)d_in[2];
  const float* Wproj = (const float*)d_in[3];
  float* out = (float*)d_out;

  char* w = (char*)d_ws;
  size_t o = 0;
  auto take = [&](size_t n) { char* p = w + o; o += (n + 255) & ~(size_t)255; return p; };
  unsigned short* xb     = (unsigned short*)take((size_t)T_TOK * HDIM * 2);
  unsigned short* WfcT   = (unsigned short*)take((size_t)NEXP * FFDIM * HDIM * 2);
  unsigned short* WprojT = (unsigned short*)take((size_t)NEXP * HDIM * FFDIM * 2);
  unsigned short* h1     = (unsigned short*)take((size_t)NPAIR * FFDIM * 2);
  int*   sel_e      = (int*)take(T_TOK * 2 * 4);
  float* sel_w      = (float*)take(T_TOK * 2 * 4);
  int*   pair_token = (int*)take(NPAIR * 4);
  float* pair_w     = (float*)take(NPAIR * 4);
  int*   counts     = (int*)take(3 * 8 * 4);
  int*   offsets    = counts + 8;
  int*   cursor     = counts + 16;

  hipMemsetAsync(out, 0, (size_t)T_TOK * HDIM * 4, stream);
  hipMemsetAsync(counts, 0, 96, stream);

  router_kernel<<<T_TOK / 4, 256, 0, stream>>>(x, Wg, xb, sel_e, sel_w, counts);
  transpose_bf16_kernel<<<dim3(FFDIM / 64, HDIM / 64, NEXP), 256, 0, stream>>>(Wfc, WfcT, HDIM, FFDIM);
  transpose_bf16_kernel<<<dim3(HDIM / 64, FFDIM / 64, NEXP), 256, 0, stream>>>(Wproj, WprojT, FFDIM, HDIM);
  offsets_kernel<<<1, 64, 0, stream>>>(counts, offsets, cursor);
  scatter_kernel<<<T_TOK / 256, 256, 0, stream>>>(sel_e, sel_w, cursor, pair_token, pair_w);

  // GEMM1: per expert, [seg x 1024] x [1024 x 4096] -> relu^2 -> h1 (bf16)
  moe_gemm_kernel<HDIM, 1, FFDIM / 256, true, true>
      <<<(FFDIM / 256) * MAXMT, 512, 0, stream>>>(xb, WfcT, counts,
                                                  pair_token, pair_w, h1, nullptr);
  // GEMM2: per expert, [seg x 4096] x [4096 x 1024] -> weighted combine, split-K=2
  moe_gemm_kernel<FFDIM, 2, HDIM / 256, false, false>
      <<<(HDIM / 256) * 2 * MAXMT, 512, 0, stream>>>(h1, WprojT, counts,
                                                     pair_token, pair_w, nullptr, out);
}